// Round 2
// baseline (1961.588 us; speedup 1.0000x reference)
//
#include <hip/hip_runtime.h>
#include <hip/hip_bf16.h>
#include <stdint.h>

#define D_DIM 1024
#define N_DIM 4096
#define C_CLS 10
#define L_IT 8
#define M_DIM 11264   // (C+1)*D

typedef __bf16 bf16_t;
typedef __bf16 bf16x8 __attribute__((ext_vector_type(8)));
typedef __bf16 bf16x4 __attribute__((ext_vector_type(4)));
typedef float  f32x4  __attribute__((ext_vector_type(4)));

__device__ __forceinline__ float bf2f(uint16_t u) {
  union { uint32_t i; float f; } x; x.i = ((uint32_t)u) << 16; return x.f;
}

// ---------------- pack fp32 -> bf16 (x4 vectorized) ----------------
__global__ void pack_bf16_k(const float4* __restrict__ src, bf16x4* __restrict__ dst, int n4) {
  int stride = gridDim.x * blockDim.x;
  for (int i = blockIdx.x * blockDim.x + threadIdx.x; i < n4; i += stride) {
    float4 v = src[i];
    bf16x4 o;
    o[0] = (bf16_t)v.x; o[1] = (bf16_t)v.y; o[2] = (bf16_t)v.z; o[3] = (bf16_t)v.w;
    dst[i] = o;
  }
}

// ---------------- transpose Zf (D x N fp32) -> ZbT (N x D bf16) ----------------
// optional fp32 copy-out (used at layer 0 to initialize Zf from the input)
__global__ __launch_bounds__(256) void transpose_zbt(const float* __restrict__ Zsrc,
                                                     bf16_t* __restrict__ ZbT,
                                                     float* __restrict__ Zf_copy) {
  __shared__ float tile[32][33];
  int tx = threadIdx.x & 31, ty = threadIdx.x >> 5;   // 32 x 8
  int nb = blockIdx.x, db = blockIdx.y;
  int n = nb * 32 + tx;
#pragma unroll
  for (int j = 0; j < 32; j += 8) {
    int d = db * 32 + ty + j;
    float v = Zsrc[(size_t)d * N_DIM + n];
    tile[ty + j][tx] = v;
    if (Zf_copy) Zf_copy[(size_t)d * N_DIM + n] = v;
  }
  __syncthreads();
  int d2 = db * 32 + tx;
#pragma unroll
  for (int j = 0; j < 32; j += 8) {
    int n2 = nb * 32 + ty + j;
    ZbT[(size_t)n2 * D_DIM + d2] = (bf16_t)tile[tx][ty + j];
  }
}

// ---------------- GEMM: OUT[M x Nc] = Wb[M x K] * ZbT^T (ZbT is N-major) ----------------
// 128x128 tile, BK=64, 4 waves each 64x64 (4x4 frags of 16x16x32 bf16 MFMA)
__global__ __launch_bounds__(256) void gemm_wz(const bf16_t* __restrict__ Wb,
                                               const bf16_t* __restrict__ ZbT,
                                               bf16_t* __restrict__ OUT, int ldo) {
  __shared__ __align__(16) bf16_t As[128 * 64];
  __shared__ __align__(16) bf16_t Bs[128 * 64];
  const int K = 1024;
  int m0 = blockIdx.x * 128;
  int n0 = blockIdx.y * 128;
  int t = threadIdx.x;
  int wave = t >> 6, lane = t & 63;
  int wm = (wave >> 1) * 64, wn = (wave & 1) * 64;
  int lr = lane >> 3;            // 0..7: row within staging chunk
  int lk = (lane & 7) * 8;       // k element offset within row (16B granule)
  int fr = lane & 15;            // fragment M/N index
  int fk = (lane >> 4) * 8;      // fragment K offset

  f32x4 acc[4][4] = {};

  const bf16_t* Abase = Wb + (size_t)m0 * K;
  const bf16_t* Bbase = ZbT + (size_t)n0 * K;

  for (int kt = 0; kt < K; kt += 64) {
#pragma unroll
    for (int j = 0; j < 4; ++j) {
      int ch = wave * 4 + j;  // 16 chunks of 1024B each for A and B
      const bf16_t* asrc = Abase + (size_t)(ch * 8 + lr) * K + kt + lk;
      __builtin_amdgcn_global_load_lds((const __attribute__((address_space(1))) void*)asrc,
                                       (__attribute__((address_space(3))) void*)(As + ch * 512),
                                       16, 0, 0);
      const bf16_t* bsrc = Bbase + (size_t)(ch * 8 + lr) * K + kt + lk;
      __builtin_amdgcn_global_load_lds((const __attribute__((address_space(1))) void*)bsrc,
                                       (__attribute__((address_space(3))) void*)(Bs + ch * 512),
                                       16, 0, 0);
    }
    __syncthreads();
#pragma unroll
    for (int ks = 0; ks < 2; ++ks) {
      bf16x8 a[4], b[4];
#pragma unroll
      for (int f = 0; f < 4; ++f)
        a[f] = *(const bf16x8*)(As + (wm + f * 16 + fr) * 64 + ks * 32 + fk);
#pragma unroll
      for (int f = 0; f < 4; ++f)
        b[f] = *(const bf16x8*)(Bs + (wn + f * 16 + fr) * 64 + ks * 32 + fk);
#pragma unroll
      for (int fm = 0; fm < 4; ++fm)
#pragma unroll
        for (int fn = 0; fn < 4; ++fn)
          acc[fm][fn] = __builtin_amdgcn_mfma_f32_16x16x32_bf16(a[fm], b[fn], acc[fm][fn], 0, 0, 0);
    }
    __syncthreads();
  }

  // epilogue: C/D layout col = lane&15, row = (lane>>4)*4 + r
  int orow = (lane >> 4) * 4;
#pragma unroll
  for (int fm = 0; fm < 4; ++fm)
#pragma unroll
    for (int fn = 0; fn < 4; ++fn) {
      int col = n0 + wn + fn * 16 + fr;
#pragma unroll
      for (int r = 0; r < 4; ++r) {
        int row = m0 + wm + fm * 16 + orow + r;
        OUT[(size_t)row * ldo + col] = (bf16_t)acc[fm][fn][r];
      }
    }
}

// ---------------- per-class column sum of squares ----------------
__global__ __launch_bounds__(256) void class_ssq(const bf16_t* __restrict__ OUT, int ldo,
                                                 float* __restrict__ ssq) {
  int c = blockIdx.y;
  int nl = blockIdx.x * 128 + (threadIdx.x & 127);
  int h = threadIdx.x >> 7;  // 0/1 halves of the i-range
  const uint16_t* base = (const uint16_t*)OUT + (size_t)(c << 10) * ldo + nl;
  float ss = 0.f;
#pragma unroll 4
  for (int i = h * 512; i < h * 512 + 512; ++i) {
    float v = bf2f(base[(size_t)i * ldo]);
    ss += v * v;
  }
  __shared__ float red[256];
  red[threadIdx.x] = ss;
  __syncthreads();
  if (threadIdx.x < 128)
    ssq[(size_t)c * ldo + nl] = red[threadIdx.x] + red[threadIdx.x + 128];
}

// ---------------- softmax over classes (in-place ssq -> P) ----------------
__global__ void softmax_p(float* __restrict__ P, int ldo, int Nc,
                          const float* __restrict__ tempr) {
  int n = blockIdx.x * 256 + threadIdx.x;
  if (n >= Nc) return;
  float invT = 1.0f / tempr[0];
  float s[C_CLS];
  float m = -1e30f;
#pragma unroll
  for (int c = 0; c < C_CLS; ++c) {
    float sim = -sqrtf(P[(size_t)c * ldo + n]);
    s[c] = sim;
    m = fmaxf(m, sim);
  }
  float sum = 0.f;
#pragma unroll
  for (int c = 0; c < C_CLS; ++c) {
    float e = __expf((s[c] - m) * invT);
    s[c] = e;
    sum += e;
  }
  float inv = 1.0f / sum;
#pragma unroll
  for (int c = 0; c < C_CLS; ++c)
    P[(size_t)c * ldo + n] = s[c] * inv;
}

// ---------------- Z update: z += eta*(G - sum_c gamma_c P_c CZ_c); accumulate norms ----------------
__global__ __launch_bounds__(256) void update_z(const bf16_t* __restrict__ OUT, int ldo, int Nc,
                                                const float* __restrict__ P,
                                                const float* __restrict__ gamma,
                                                const float* __restrict__ etap,
                                                float* __restrict__ Zf, int n_off,
                                                float* __restrict__ normsq) {
  int nl = blockIdx.x * 256 + threadIdx.x;
  if (nl >= Nc) return;
  int n = n_off + nl;
  int i0 = blockIdx.y * 64;
  float eta = etap[0];
  float gP[C_CLS];
#pragma unroll
  for (int c = 0; c < C_CLS; ++c) gP[c] = gamma[c] * P[(size_t)c * ldo + nl];
  const uint16_t* ob = (const uint16_t*)OUT + nl;
  float ss = 0.f;
  for (int i = i0; i < i0 + 64; ++i) {
    float term = 0.f;
#pragma unroll
    for (int c = 0; c < C_CLS; ++c)
      term += gP[c] * bf2f(ob[(size_t)((c << 10) + i) * ldo]);
    float g = bf2f(ob[(size_t)(10240 + i) * ldo]);
    float z = Zf[(size_t)i * N_DIM + n];
    float zn = z + eta * (g - term);
    Zf[(size_t)i * N_DIM + n] = zn;
    ss += zn * zn;
  }
  atomicAdd(&normsq[n], ss);
}

// ---------------- column-normalize in place (Zf aliases d_out, fp32) ----------------
__global__ void normalize_z(float* __restrict__ Zf, const float* __restrict__ normsq) {
  int n = blockIdx.x * 256 + threadIdx.x;
  int i = blockIdx.y;
  float inv = rsqrtf(normsq[n]);
  Zf[(size_t)i * N_DIM + n] *= inv;
}

extern "C" void kernel_launch(void* const* d_in, const int* in_sizes, int n_in,
                              void* d_out, int out_size, void* d_ws, size_t ws_size,
                              hipStream_t stream) {
  (void)in_sizes; (void)n_in; (void)out_size;
  const float* Zin        = (const float*)d_in[0];
  const float* Elist      = (const float*)d_in[1];
  const float* Cslist     = (const float*)d_in[2];
  const float* gamma      = (const float*)d_in[3];
  const float* eta        = (const float*)d_in[4];
  const float* temperature= (const float*)d_in[5];

  // Zf (the evolving D x N fp32 feature matrix) lives directly in d_out:
  // it is fully initialized at layer 0 and holds the final normalized Z
  // after the last layer. Output dtype is float32 (reference returns f32).
  float* Zf = (float*)d_out;

  auto align256 = [](size_t x) { return (x + 255) & ~(size_t)255; };
  size_t zbt_b = align256((size_t)N_DIM * D_DIM * 2);
  size_t wb_b  = align256((size_t)M_DIM * D_DIM * 2);
  size_t ns_b  = align256((size_t)N_DIM * 4);
  size_t fixed = zbt_b + wb_b + ns_b;

  int Nc = N_DIM;
  while (Nc > 128) {
    size_t need = fixed + align256((size_t)C_CLS * Nc * 4) + align256((size_t)M_DIM * Nc * 2);
    if (need <= ws_size) break;
    Nc >>= 1;
  }
  if (fixed + align256((size_t)C_CLS * Nc * 4) + align256((size_t)M_DIM * Nc * 2) > ws_size) {
    hipMemsetAsync(d_out, 0, (size_t)D_DIM * N_DIM * 4, stream);  // clean-fail signal
    return;
  }

  char* p = (char*)d_ws;
  bf16_t* ZbT    = (bf16_t*)p; p += zbt_b;
  bf16_t* Wb     = (bf16_t*)p; p += wb_b;
  float*  normsq = (float*)p;  p += ns_b;
  float*  Pbuf   = (float*)p;  p += align256((size_t)C_CLS * Nc * 4);
  bf16_t* OUT    = (bf16_t*)p;

  for (int l = 0; l < L_IT; ++l) {
    const float* Cs = Cslist + (size_t)l * C_CLS * D_DIM * D_DIM;
    const float* El = Elist  + (size_t)l * D_DIM * D_DIM;
    // pack W = [Cs ; E] -> bf16
    pack_bf16_k<<<2048, 256, 0, stream>>>((const float4*)Cs, (bf16x4*)Wb,
                                          C_CLS * D_DIM * D_DIM / 4);
    pack_bf16_k<<<1024, 256, 0, stream>>>((const float4*)El,
                                          (bf16x4*)(Wb + (size_t)C_CLS * D_DIM * D_DIM),
                                          D_DIM * D_DIM / 4);
    // Z -> N-major bf16 (layer 0: from input, also copy into Zf = d_out)
    transpose_zbt<<<dim3(N_DIM / 32, D_DIM / 32), 256, 0, stream>>>(
        l == 0 ? Zin : Zf, ZbT, l == 0 ? Zf : nullptr);
    hipMemsetAsync(normsq, 0, (size_t)N_DIM * 4, stream);

    for (int n_off = 0; n_off < N_DIM; n_off += Nc) {
      gemm_wz<<<dim3(M_DIM / 128, Nc / 128), 256, 0, stream>>>(
          Wb, ZbT + (size_t)n_off * D_DIM, OUT, Nc);
      class_ssq<<<dim3(Nc / 128, C_CLS), 256, 0, stream>>>(OUT, Nc, Pbuf);
      softmax_p<<<(Nc + 255) / 256, 256, 0, stream>>>(Pbuf, Nc, Nc, temperature);
      update_z<<<dim3((Nc + 255) / 256, D_DIM / 64), 256, 0, stream>>>(
          OUT, Nc, Nc, Pbuf, gamma, eta, Zf, n_off, normsq);
    }
    normalize_z<<<dim3(N_DIM / 256, D_DIM), 256, 0, stream>>>(Zf, normsq);
  }
}

// Round 3
// 1717.103 us; speedup vs baseline: 1.1424x; 1.1424x over previous
//
#include <hip/hip_runtime.h>
#include <hip/hip_bf16.h>
#include <stdint.h>

#define D_DIM 1024
#define N_DIM 4096
#define C_CLS 10
#define L_IT 8
#define M_DIM 11264   // (C+1)*D
#define NBM 44        // M_DIM / 256

typedef __bf16 bf16_t;
typedef __bf16 bf16x8 __attribute__((ext_vector_type(8)));
typedef __bf16 bf16x4 __attribute__((ext_vector_type(4)));
typedef float  f32x4  __attribute__((ext_vector_type(4)));

__device__ __forceinline__ float bf2f(uint16_t u) {
  union { uint32_t i; float f; } x; x.i = ((uint32_t)u) << 16; return x.f;
}

// ---------------- pack fp32 -> bf16 (x4 vectorized) ----------------
__global__ void pack_bf16_k(const float4* __restrict__ src, bf16x4* __restrict__ dst, int n4) {
  int stride = gridDim.x * blockDim.x;
  for (int i = blockIdx.x * blockDim.x + threadIdx.x; i < n4; i += stride) {
    float4 v = src[i];
    bf16x4 o;
    o[0] = (bf16_t)v.x; o[1] = (bf16_t)v.y; o[2] = (bf16_t)v.z; o[3] = (bf16_t)v.w;
    dst[i] = o;
  }
}

// ---------------- transpose Zf (D x N fp32) -> ZbT (N x D bf16) ----------------
__global__ __launch_bounds__(256) void transpose_zbt(const float* __restrict__ Zsrc,
                                                     bf16_t* __restrict__ ZbT,
                                                     float* __restrict__ Zf_copy) {
  __shared__ float tile[32][33];
  int tx = threadIdx.x & 31, ty = threadIdx.x >> 5;   // 32 x 8
  int nb = blockIdx.x, db = blockIdx.y;
  int n = nb * 32 + tx;
#pragma unroll
  for (int j = 0; j < 32; j += 8) {
    int d = db * 32 + ty + j;
    float v = Zsrc[(size_t)d * N_DIM + n];
    tile[ty + j][tx] = v;
    if (Zf_copy) Zf_copy[(size_t)d * N_DIM + n] = v;
  }
  __syncthreads();
  int d2 = db * 32 + tx;
#pragma unroll
  for (int j = 0; j < 32; j += 8) {
    int n2 = nb * 32 + ty + j;
    ZbT[(size_t)n2 * D_DIM + d2] = (bf16_t)tile[tx][ty + j];
  }
}

// ================= 256x256 8-phase GEMM (T1+T2+T3/T4+T5) =================
// OUT[M x Nc] = Wb[M x 1024] * ZbT^T (ZbT is N-major [N x 1024])
// 512 threads = 8 waves (2M x 4N), per-wave 128x64 output, BK=64, K=1024 (16 tiles).
// LDS 128 KiB: A bufs at 0 / 16384, B bufs at 32768 / 49152 (elements).
// Half-tiles are quadrant-read unions: A half = qm rows {0-63 u 128-191}(h0) etc.
// Swizzle (T2): 16B slot s -> s ^ (row&7), applied on pre-swizzled global src + ds_read.

#define STAGE_A(buf, h, t) do {                                                         \
    _Pragma("unroll") for (int e_ = 0; e_ < 2; ++e_) {                                  \
      const bf16_t* s_ = Wb + aoff0[e_] + (size_t)(h) * 65536 + (size_t)(t) * 64;       \
      __builtin_amdgcn_global_load_lds(                                                 \
        (const __attribute__((address_space(1))) void*)s_,                              \
        (__attribute__((address_space(3))) void*)(lds + (buf)*16384 + (h)*8192 + dstslot[e_]), \
        16, 0, 0);                                                                      \
    } } while (0)

#define STAGE_B(buf, h, t) do {                                                         \
    _Pragma("unroll") for (int e_ = 0; e_ < 2; ++e_) {                                  \
      const bf16_t* s_ = ZbT + boff0[e_] + (size_t)(h) * 32768 + (size_t)(t) * 64;      \
      __builtin_amdgcn_global_load_lds(                                                 \
        (const __attribute__((address_space(1))) void*)s_,                              \
        (__attribute__((address_space(3))) void*)(lds + 32768 + (buf)*16384 + (h)*8192 + dstslot[e_]), \
        16, 0, 0);                                                                      \
    } } while (0)

#define LOAD_A(buf, qm) do {                                                            \
    _Pragma("unroll") for (int f_ = 0; f_ < 4; ++f_)                                    \
      _Pragma("unroll") for (int kk_ = 0; kk_ < 2; ++kk_)                               \
        a[f_][kk_] = *(const bf16x8*)(lds + (buf)*16384 + (qm)*8192 + aRowBase + f_*1024 + sidx[kk_]); \
  } while (0)

#define LOAD_B(buf, qn) do {                                                            \
    _Pragma("unroll") for (int f_ = 0; f_ < 2; ++f_)                                    \
      _Pragma("unroll") for (int kk_ = 0; kk_ < 2; ++kk_)                               \
        b[f_][kk_] = *(const bf16x8*)(lds + 32768 + (buf)*16384 + (qn)*8192 + bRowBase + f_*1024 + sidx[kk_]); \
  } while (0)

#define MFMA_Q(qm, qn) do {                                                             \
    _Pragma("unroll") for (int mm_ = 0; mm_ < 4; ++mm_)                                 \
      _Pragma("unroll") for (int nn_ = 0; nn_ < 2; ++nn_)                               \
        _Pragma("unroll") for (int kk_ = 0; kk_ < 2; ++kk_)                             \
          acc[(qm)*4+mm_][(qn)*2+nn_] = __builtin_amdgcn_mfma_f32_16x16x32_bf16(        \
            a[mm_][kk_], b[nn_][kk_], acc[(qm)*4+mm_][(qn)*2+nn_], 0, 0, 0);            \
  } while (0)

#define PHASE(buf, qm, qn, DO_LOADA, STAGE_STMT, WAIT_STMT) do {                        \
    if (DO_LOADA) LOAD_A(buf, qm);                                                      \
    LOAD_B(buf, qn);                                                                    \
    STAGE_STMT;                                                                         \
    __builtin_amdgcn_s_barrier();                                                       \
    asm volatile("s_waitcnt lgkmcnt(0)" ::: "memory");                                  \
    __builtin_amdgcn_sched_barrier(0);                                                  \
    __builtin_amdgcn_s_setprio(1);                                                      \
    MFMA_Q(qm, qn);                                                                     \
    __builtin_amdgcn_s_setprio(0);                                                      \
    WAIT_STMT;                                                                          \
    __builtin_amdgcn_s_barrier();                                                       \
  } while (0)

__global__ __launch_bounds__(512, 2) void gemm_wz8(const bf16_t* __restrict__ Wb,
                                                   const bf16_t* __restrict__ ZbT,
                                                   bf16_t* __restrict__ OUT, int ldo) {
  __shared__ __align__(16) bf16_t lds[65536];  // 128 KiB

  // T1: bijective XCD swizzle (m204)
  int nwg = gridDim.x;
  int bid = blockIdx.x;
  int q = nwg >> 3, r = nwg & 7;
  int xcd = bid & 7, idx = bid >> 3;
  int swz = (xcd < r ? xcd * (q + 1) : r * (q + 1) + (xcd - r) * q) + idx;
  int bm = swz % NBM, bn = swz / NBM;
  int m0 = bm * 256, n0 = bn * 256;

  int tid = threadIdx.x;
  int wave = tid >> 6, lane = tid & 63;
  int wrow = wave >> 2, wcol = wave & 3;
  int lm = lane & 15, lks = lane >> 4;   // 0..3
  int sw = lm & 7;

  // staging precompute: slot j = e*512 + tid; rih = j>>3 (row in half), sl = j&7
  size_t aoff0[2], boff0[2];
  int dstslot[2];
#pragma unroll
  for (int e = 0; e < 2; ++e) {
    int j = e * 512 + tid;
    int rih = j >> 3, sl = j & 7;
    int sg = sl ^ (rih & 7);                       // pre-swizzled global 16B slot
    int arow = (rih & 63) + ((rih >> 6) << 7);     // A: h adds +64 rows
    int brow = (rih & 31) + ((rih >> 5) << 6);     // B: h adds +32 rows
    aoff0[e] = (size_t)(m0 + arow) * 1024 + sg * 8;
    boff0[e] = (size_t)(n0 + brow) * 1024 + sg * 8;
    dstslot[e] = e * 4096 + wave * 512;            // element offset (wave-uniform)
  }

  // ds-read precompute
  int aRowBase = (wrow * 64 + lm) * 64;
  int bRowBase = (wcol * 32 + lm) * 64;
  int sidx[2] = { ((0 + lks) ^ sw) * 8, ((4 + lks) ^ sw) * 8 };

  f32x4 acc[8][4] = {};
  bf16x8 a[4][2], b[2][2];

  // prologue: T0 complete + T1.{A0,B0}; leave {T1.A0,T1.B0} outstanding
  STAGE_A(0, 0, 0); STAGE_A(0, 1, 0); STAGE_B(0, 0, 0); STAGE_B(0, 1, 0);
  STAGE_A(1, 0, 1); STAGE_B(1, 0, 1);
  asm volatile("s_waitcnt vmcnt(4)" ::: "memory");
  __builtin_amdgcn_s_barrier();

  // steady state: iterations compute tiles E=2it (buf0), O=2it+1 (buf1);
  // issue O.{A1,B1} (ph1,2), N=E+2 into buf0 (ph3-6), M=O+2 into buf1 (ph7,8).
  for (int it = 0; it < 7; ++it) {
    int tO = 2 * it + 1, tN = 2 * it + 2, tM = 2 * it + 3;
    PHASE(0, 0, 0, 1, STAGE_A(1, 1, tO), );
    PHASE(0, 0, 1, 0, STAGE_B(1, 1, tO), );
    PHASE(0, 1, 0, 1, STAGE_A(0, 0, tN), );
    PHASE(0, 1, 1, 0, STAGE_A(0, 1, tN), asm volatile("s_waitcnt vmcnt(4)" ::: "memory"));
    PHASE(1, 0, 0, 1, STAGE_B(0, 0, tN), );
    PHASE(1, 0, 1, 0, STAGE_B(0, 1, tN), );
    PHASE(1, 1, 0, 1, STAGE_A(1, 0, tM), );
    PHASE(1, 1, 1, 0, STAGE_B(1, 0, tM), asm volatile("s_waitcnt vmcnt(4)" ::: "memory"));
  }
  // epilogue: tiles 14 (buf0), 15 (buf1); finish staging 15.{A1,B1}, drain at ph4
  PHASE(0, 0, 0, 1, STAGE_A(1, 1, 15), );
  PHASE(0, 0, 1, 0, STAGE_B(1, 1, 15), );
  PHASE(0, 1, 0, 1, , );
  PHASE(0, 1, 1, 0, , asm volatile("s_waitcnt vmcnt(0)" ::: "memory"));
  PHASE(1, 0, 0, 1, , );
  PHASE(1, 0, 1, 0, , );
  PHASE(1, 1, 0, 1, , );
  PHASE(1, 1, 1, 0, , );

  // C-write: col = lane&15, row = (lane>>4)*4 + rr
  int orow = (lane >> 4) * 4;
#pragma unroll
  for (int mf = 0; mf < 8; ++mf)
#pragma unroll
    for (int nf = 0; nf < 4; ++nf) {
      int col = n0 + wcol * 64 + nf * 16 + lm;
      size_t rb = (size_t)(m0 + wrow * 128 + mf * 16 + orow) * ldo + col;
#pragma unroll
      for (int rr = 0; rr < 4; ++rr)
        OUT[rb + (size_t)rr * ldo] = (bf16_t)acc[mf][nf][rr];
    }
}

// ---------------- per-class column sum of squares ----------------
__global__ __launch_bounds__(256) void class_ssq(const bf16_t* __restrict__ OUT, int ldo,
                                                 float* __restrict__ ssq) {
  int c = blockIdx.y;
  int nl = blockIdx.x * 128 + (threadIdx.x & 127);
  int h = threadIdx.x >> 7;
  const uint16_t* base = (const uint16_t*)OUT + (size_t)(c << 10) * ldo + nl;
  float ss = 0.f;
#pragma unroll 4
  for (int i = h * 512; i < h * 512 + 512; ++i) {
    float v = bf2f(base[(size_t)i * ldo]);
    ss += v * v;
  }
  __shared__ float red[256];
  red[threadIdx.x] = ss;
  __syncthreads();
  if (threadIdx.x < 128)
    ssq[(size_t)c * ldo + nl] = red[threadIdx.x] + red[threadIdx.x + 128];
}

// ---------------- softmax over classes (in-place ssq -> P) ----------------
__global__ void softmax_p(float* __restrict__ P, int ldo, int Nc,
                          const float* __restrict__ tempr) {
  int n = blockIdx.x * 256 + threadIdx.x;
  if (n >= Nc) return;
  float invT = 1.0f / tempr[0];
  float s[C_CLS];
  float m = -1e30f;
#pragma unroll
  for (int c = 0; c < C_CLS; ++c) {
    float sim = -sqrtf(P[(size_t)c * ldo + n]);
    s[c] = sim;
    m = fmaxf(m, sim);
  }
  float sum = 0.f;
#pragma unroll
  for (int c = 0; c < C_CLS; ++c) {
    float e = __expf((s[c] - m) * invT);
    s[c] = e;
    sum += e;
  }
  float inv = 1.0f / sum;
#pragma unroll
  for (int c = 0; c < C_CLS; ++c)
    P[(size_t)c * ldo + n] = s[c] * inv;
}

// ---------------- Z update: z += eta*(G - sum_c gamma_c P_c CZ_c) ----------------
__global__ __launch_bounds__(256) void update_z(const bf16_t* __restrict__ OUT, int ldo, int Nc,
                                                const float* __restrict__ P,
                                                const float* __restrict__ gamma,
                                                const float* __restrict__ etap,
                                                float* __restrict__ Zf, int n_off,
                                                float* __restrict__ normsq) {
  int nl = blockIdx.x * 256 + threadIdx.x;
  if (nl >= Nc) return;
  int n = n_off + nl;
  int i0 = blockIdx.y * 64;
  float eta = etap[0];
  float gP[C_CLS];
#pragma unroll
  for (int c = 0; c < C_CLS; ++c) gP[c] = gamma[c] * P[(size_t)c * ldo + nl];
  const uint16_t* ob = (const uint16_t*)OUT + nl;
  float ss = 0.f;
  for (int i = i0; i < i0 + 64; ++i) {
    float term = 0.f;
#pragma unroll
    for (int c = 0; c < C_CLS; ++c)
      term += gP[c] * bf2f(ob[(size_t)((c << 10) + i) * ldo]);
    float g = bf2f(ob[(size_t)(10240 + i) * ldo]);
    float z = Zf[(size_t)i * N_DIM + n];
    float zn = z + eta * (g - term);
    Zf[(size_t)i * N_DIM + n] = zn;
    ss += zn * zn;
  }
  atomicAdd(&normsq[n], ss);
}

// ---------------- column-normalize in place (Zf aliases d_out, fp32) ----------------
__global__ void normalize_z(float* __restrict__ Zf, const float* __restrict__ normsq) {
  int n = blockIdx.x * 256 + threadIdx.x;
  int i = blockIdx.y;
  float inv = rsqrtf(normsq[n]);
  Zf[(size_t)i * N_DIM + n] *= inv;
}

extern "C" void kernel_launch(void* const* d_in, const int* in_sizes, int n_in,
                              void* d_out, int out_size, void* d_ws, size_t ws_size,
                              hipStream_t stream) {
  (void)in_sizes; (void)n_in; (void)out_size;
  const float* Zin        = (const float*)d_in[0];
  const float* Elist      = (const float*)d_in[1];
  const float* Cslist     = (const float*)d_in[2];
  const float* gamma      = (const float*)d_in[3];
  const float* eta        = (const float*)d_in[4];
  const float* temperature= (const float*)d_in[5];

  float* Zf = (float*)d_out;  // evolving D x N fp32 features live in d_out

  auto align256 = [](size_t x) { return (x + 255) & ~(size_t)255; };
  size_t zbt_b = align256((size_t)N_DIM * D_DIM * 2);
  size_t wb_b  = align256((size_t)M_DIM * D_DIM * 2);
  size_t ns_b  = align256((size_t)N_DIM * 4);
  size_t fixed = zbt_b + wb_b + ns_b;

  int Nc = N_DIM;
  while (Nc > 256) {
    size_t need = fixed + align256((size_t)C_CLS * Nc * 4) + align256((size_t)M_DIM * Nc * 2);
    if (need <= ws_size) break;
    Nc >>= 1;
  }
  if (fixed + align256((size_t)C_CLS * Nc * 4) + align256((size_t)M_DIM * Nc * 2) > ws_size) {
    hipMemsetAsync(d_out, 0, (size_t)D_DIM * N_DIM * 4, stream);  // clean-fail signal
    return;
  }

  char* p = (char*)d_ws;
  bf16_t* ZbT    = (bf16_t*)p; p += zbt_b;
  bf16_t* Wb     = (bf16_t*)p; p += wb_b;
  float*  normsq = (float*)p;  p += ns_b;
  float*  Pbuf   = (float*)p;  p += align256((size_t)C_CLS * Nc * 4);
  bf16_t* OUT    = (bf16_t*)p;

  for (int l = 0; l < L_IT; ++l) {
    const float* Cs = Cslist + (size_t)l * C_CLS * D_DIM * D_DIM;
    const float* El = Elist  + (size_t)l * D_DIM * D_DIM;
    pack_bf16_k<<<2048, 256, 0, stream>>>((const float4*)Cs, (bf16x4*)Wb,
                                          C_CLS * D_DIM * D_DIM / 4);
    pack_bf16_k<<<1024, 256, 0, stream>>>((const float4*)El,
                                          (bf16x4*)(Wb + (size_t)C_CLS * D_DIM * D_DIM),
                                          D_DIM * D_DIM / 4);
    transpose_zbt<<<dim3(N_DIM / 32, D_DIM / 32), 256, 0, stream>>>(
        l == 0 ? Zin : Zf, ZbT, l == 0 ? Zf : nullptr);
    hipMemsetAsync(normsq, 0, (size_t)N_DIM * 4, stream);

    for (int n_off = 0; n_off < N_DIM; n_off += Nc) {
      gemm_wz8<<<dim3(NBM * (Nc / 256)), 512, 0, stream>>>(
          Wb, ZbT + (size_t)n_off * D_DIM, OUT, Nc);
      class_ssq<<<dim3(Nc / 128, C_CLS), 256, 0, stream>>>(OUT, Nc, Pbuf);
      softmax_p<<<(Nc + 255) / 256, 256, 0, stream>>>(Pbuf, Nc, Nc, temperature);
      update_z<<<dim3((Nc + 255) / 256, D_DIM / 64), 256, 0, stream>>>(
          OUT, Nc, Nc, Pbuf, gamma, eta, Zf, n_off, normsq);
    }
    normalize_z<<<dim3(N_DIM / 256, D_DIM), 256, 0, stream>>>(Zf, normsq);
  }
}

// Round 4
// 1314.193 us; speedup vs baseline: 1.4926x; 1.3066x over previous
//
#include <hip/hip_runtime.h>
#include <hip/hip_bf16.h>
#include <stdint.h>

#define D_DIM 1024
#define N_DIM 4096
#define C_CLS 10
#define L_IT 8
#define M_DIM 11264   // (C+1)*D
#define NBM 44        // M_DIM / 256

typedef __bf16 bf16_t;
typedef __bf16 bf16x8 __attribute__((ext_vector_type(8)));
typedef __bf16 bf16x4 __attribute__((ext_vector_type(4)));
typedef float  f32x4  __attribute__((ext_vector_type(4)));

__device__ __forceinline__ float bf2f(uint16_t u) {
  union { uint32_t i; float f; } x; x.i = ((uint32_t)u) << 16; return x.f;
}

// ---------------- pack fp32 -> bf16 (x4 vectorized) ----------------
__global__ void pack_bf16_k(const float4* __restrict__ src, bf16x4* __restrict__ dst, int n4) {
  int stride = gridDim.x * blockDim.x;
  for (int i = blockIdx.x * blockDim.x + threadIdx.x; i < n4; i += stride) {
    float4 v = src[i];
    bf16x4 o;
    o[0] = (bf16_t)v.x; o[1] = (bf16_t)v.y; o[2] = (bf16_t)v.z; o[3] = (bf16_t)v.w;
    dst[i] = o;
  }
}

// ---------------- transpose (D x N fp32) -> ZbT (N x D bf16), scaling by rsqrt(normsq) ----------------
// normsq == null -> no scale (layer 0). Zf_copy: optional raw fp32 copy-out (layer 0).
__global__ __launch_bounds__(256) void transpose_zbt(const float* __restrict__ Zsrc,
                                                     bf16_t* __restrict__ ZbT,
                                                     float* __restrict__ Zf_copy,
                                                     const float* __restrict__ normsq) {
  __shared__ float tile[32][33];
  int tx = threadIdx.x & 31, ty = threadIdx.x >> 5;   // 32 x 8
  int nb = blockIdx.x, db = blockIdx.y;
  int n = nb * 32 + tx;
  float inv = normsq ? rsqrtf(normsq[n]) : 1.0f;
#pragma unroll
  for (int j = 0; j < 32; j += 8) {
    int d = db * 32 + ty + j;
    float v = Zsrc[(size_t)d * N_DIM + n];
    if (Zf_copy) Zf_copy[(size_t)d * N_DIM + n] = v;
    tile[ty + j][tx] = v * inv;
  }
  __syncthreads();
  int d2 = db * 32 + tx;
#pragma unroll
  for (int j = 0; j < 32; j += 8) {
    int n2 = nb * 32 + ty + j;
    ZbT[(size_t)n2 * D_DIM + d2] = (bf16_t)tile[tx][ty + j];
  }
}

// ================= 256x256 8-phase GEMM (T1+T2+T3/T4+T5) + fused class-ssq =================
// OUT[M x Nc] = Wb[M x 1024] * ZbT^T (ZbT is N-major [N x 1024])
// 512 threads = 8 waves (2M x 4N), per-wave 128x64 output, BK=64, K=1024 (16 tiles).
// LDS 128 KiB: A bufs at 0 / 16384, B bufs at 32768 / 49152 (elements).
// Swizzle (T2): 16B slot s -> s ^ (row&7), on pre-swizzled global src + ds_read.
// Epilogue additionally accumulates per-(class, column) sum-of-squares into ssq.

#define STAGE_A(buf, h, t) do {                                                         \
    _Pragma("unroll") for (int e_ = 0; e_ < 2; ++e_) {                                  \
      const bf16_t* s_ = Wb + aoff0[e_] + (size_t)(h) * 65536 + (size_t)(t) * 64;       \
      __builtin_amdgcn_global_load_lds(                                                 \
        (const __attribute__((address_space(1))) void*)s_,                              \
        (__attribute__((address_space(3))) void*)(lds + (buf)*16384 + (h)*8192 + dstslot[e_]), \
        16, 0, 0);                                                                      \
    } } while (0)

#define STAGE_B(buf, h, t) do {                                                         \
    _Pragma("unroll") for (int e_ = 0; e_ < 2; ++e_) {                                  \
      const bf16_t* s_ = ZbT + boff0[e_] + (size_t)(h) * 32768 + (size_t)(t) * 64;      \
      __builtin_amdgcn_global_load_lds(                                                 \
        (const __attribute__((address_space(1))) void*)s_,                              \
        (__attribute__((address_space(3))) void*)(lds + 32768 + (buf)*16384 + (h)*8192 + dstslot[e_]), \
        16, 0, 0);                                                                      \
    } } while (0)

#define LOAD_A(buf, qm) do {                                                            \
    _Pragma("unroll") for (int f_ = 0; f_ < 4; ++f_)                                    \
      _Pragma("unroll") for (int kk_ = 0; kk_ < 2; ++kk_)                               \
        a[f_][kk_] = *(const bf16x8*)(lds + (buf)*16384 + (qm)*8192 + aRowBase + f_*1024 + sidx[kk_]); \
  } while (0)

#define LOAD_B(buf, qn) do {                                                            \
    _Pragma("unroll") for (int f_ = 0; f_ < 2; ++f_)                                    \
      _Pragma("unroll") for (int kk_ = 0; kk_ < 2; ++kk_)                               \
        b[f_][kk_] = *(const bf16x8*)(lds + 32768 + (buf)*16384 + (qn)*8192 + bRowBase + f_*1024 + sidx[kk_]); \
  } while (0)

#define MFMA_Q(qm, qn) do {                                                             \
    _Pragma("unroll") for (int mm_ = 0; mm_ < 4; ++mm_)                                 \
      _Pragma("unroll") for (int nn_ = 0; nn_ < 2; ++nn_)                               \
        _Pragma("unroll") for (int kk_ = 0; kk_ < 2; ++kk_)                             \
          acc[(qm)*4+mm_][(qn)*2+nn_] = __builtin_amdgcn_mfma_f32_16x16x32_bf16(        \
            a[mm_][kk_], b[nn_][kk_], acc[(qm)*4+mm_][(qn)*2+nn_], 0, 0, 0);            \
  } while (0)

#define PHASE(buf, qm, qn, DO_LOADA, STAGE_STMT, WAIT_STMT) do {                        \
    if (DO_LOADA) LOAD_A(buf, qm);                                                      \
    LOAD_B(buf, qn);                                                                    \
    STAGE_STMT;                                                                         \
    __builtin_amdgcn_s_barrier();                                                       \
    asm volatile("s_waitcnt lgkmcnt(0)" ::: "memory");                                  \
    __builtin_amdgcn_sched_barrier(0);                                                  \
    __builtin_amdgcn_s_setprio(1);                                                      \
    MFMA_Q(qm, qn);                                                                     \
    __builtin_amdgcn_s_setprio(0);                                                      \
    WAIT_STMT;                                                                          \
    __builtin_amdgcn_s_barrier();                                                       \
  } while (0)

__global__ __launch_bounds__(512, 2) void gemm_wz8(const bf16_t* __restrict__ Wb,
                                                   const bf16_t* __restrict__ ZbT,
                                                   bf16_t* __restrict__ OUT, int ldo,
                                                   float* __restrict__ ssq) {
  __shared__ __align__(16) bf16_t lds[65536];  // 128 KiB

  // T1: bijective XCD swizzle (m204)
  int nwg = gridDim.x;
  int bid = blockIdx.x;
  int q = nwg >> 3, r = nwg & 7;
  int xcd = bid & 7, idx = bid >> 3;
  int swz = (xcd < r ? xcd * (q + 1) : r * (q + 1) + (xcd - r) * q) + idx;
  int bm = swz % NBM, bn = swz / NBM;
  int m0 = bm * 256, n0 = bn * 256;

  int tid = threadIdx.x;
  int wave = tid >> 6, lane = tid & 63;
  int wrow = wave >> 2, wcol = wave & 3;
  int lm = lane & 15, lks = lane >> 4;   // 0..3
  int sw = lm & 7;

  // staging precompute
  size_t aoff0[2], boff0[2];
  int dstslot[2];
#pragma unroll
  for (int e = 0; e < 2; ++e) {
    int j = e * 512 + tid;
    int rih = j >> 3, sl = j & 7;
    int sg = sl ^ (rih & 7);                       // pre-swizzled global 16B slot
    int arow = (rih & 63) + ((rih >> 6) << 7);     // A: h adds +64 rows
    int brow = (rih & 31) + ((rih >> 5) << 6);     // B: h adds +32 rows
    aoff0[e] = (size_t)(m0 + arow) * 1024 + sg * 8;
    boff0[e] = (size_t)(n0 + brow) * 1024 + sg * 8;
    dstslot[e] = e * 4096 + wave * 512;            // element offset (wave-uniform)
  }

  // ds-read precompute
  int aRowBase = (wrow * 64 + lm) * 64;
  int bRowBase = (wcol * 32 + lm) * 64;
  int sidx[2] = { ((0 + lks) ^ sw) * 8, ((4 + lks) ^ sw) * 8 };

  f32x4 acc[8][4] = {};
  bf16x8 a[4][2], b[2][2];

  // prologue: T0 complete + T1.{A0,B0}; leave {T1.A0,T1.B0} outstanding
  STAGE_A(0, 0, 0); STAGE_A(0, 1, 0); STAGE_B(0, 0, 0); STAGE_B(0, 1, 0);
  STAGE_A(1, 0, 1); STAGE_B(1, 0, 1);
  asm volatile("s_waitcnt vmcnt(4)" ::: "memory");
  __builtin_amdgcn_s_barrier();

  for (int it = 0; it < 7; ++it) {
    int tO = 2 * it + 1, tN = 2 * it + 2, tM = 2 * it + 3;
    PHASE(0, 0, 0, 1, STAGE_A(1, 1, tO), );
    PHASE(0, 0, 1, 0, STAGE_B(1, 1, tO), );
    PHASE(0, 1, 0, 1, STAGE_A(0, 0, tN), );
    PHASE(0, 1, 1, 0, STAGE_A(0, 1, tN), asm volatile("s_waitcnt vmcnt(4)" ::: "memory"));
    PHASE(1, 0, 0, 1, STAGE_B(0, 0, tN), );
    PHASE(1, 0, 1, 0, STAGE_B(0, 1, tN), );
    PHASE(1, 1, 0, 1, STAGE_A(1, 0, tM), );
    PHASE(1, 1, 1, 0, STAGE_B(1, 0, tM), asm volatile("s_waitcnt vmcnt(4)" ::: "memory"));
  }
  PHASE(0, 0, 0, 1, STAGE_A(1, 1, 15), );
  PHASE(0, 0, 1, 0, STAGE_B(1, 1, 15), );
  PHASE(0, 1, 0, 1, , );
  PHASE(0, 1, 1, 0, , asm volatile("s_waitcnt vmcnt(0)" ::: "memory"));
  PHASE(1, 0, 0, 1, , );
  PHASE(1, 0, 1, 0, , );
  PHASE(1, 1, 0, 1, , );
  PHASE(1, 1, 1, 0, , );

  // C-write: col = lane&15, row = (lane>>4)*4 + rr
  int orow = (lane >> 4) * 4;
#pragma unroll
  for (int mf = 0; mf < 8; ++mf)
#pragma unroll
    for (int nf = 0; nf < 4; ++nf) {
      int col = n0 + wcol * 64 + nf * 16 + lm;
      size_t rb = (size_t)(m0 + wrow * 128 + mf * 16 + orow) * ldo + col;
#pragma unroll
      for (int rr = 0; rr < 4; ++rr)
        OUT[rb + (size_t)rr * ldo] = (bf16_t)acc[mf][nf][rr];
    }

  // fused per-class column sum-of-squares (class blocks only; E rows skip)
  if (m0 < C_CLS * 1024) {
    int c = m0 >> 10;   // 256-row block lies entirely within one 1024-row class
#pragma unroll
    for (int nf = 0; nf < 4; ++nf) {
      float v = 0.f;
#pragma unroll
      for (int mf = 0; mf < 8; ++mf)
#pragma unroll
        for (int rr = 0; rr < 4; ++rr)
          v += acc[mf][nf][rr] * acc[mf][nf][rr];
      v += __shfl_xor(v, 16);
      v += __shfl_xor(v, 32);
      if (lks == 0)
        atomicAdd(&ssq[(size_t)c * ldo + n0 + wcol * 64 + nf * 16 + lm], v);
    }
  }
}

// ---------------- fused softmax + Z update ----------------
// P from ssq per column; z scaled by rsqrt(normsq_old) on read (deferred norm);
// writes unnormalized U_{l+1}; accumulates new column norms.
__global__ __launch_bounds__(256) void update_fused(const bf16_t* __restrict__ OUT, int ldo, int Nc,
                                                    const float* __restrict__ ssq,
                                                    const float* __restrict__ gamma,
                                                    const float* __restrict__ etap,
                                                    const float* __restrict__ tempr,
                                                    const float* __restrict__ normsq_old,
                                                    float* __restrict__ Zf, int n_off,
                                                    float* __restrict__ normsq_new) {
  int nl = blockIdx.x * 256 + threadIdx.x;
  if (nl >= Nc) return;
  int n = n_off + nl;
  int i0 = blockIdx.y * 64;
  float eta = etap[0], invT = 1.0f / tempr[0];
  float zs = normsq_old ? rsqrtf(normsq_old[n]) : 1.0f;

  // softmax over classes from ssq
  float s[C_CLS], m = -1e30f;
#pragma unroll
  for (int c = 0; c < C_CLS; ++c) {
    float sim = -sqrtf(ssq[(size_t)c * ldo + nl]);
    s[c] = sim;
    m = fmaxf(m, sim);
  }
  float sum = 0.f;
#pragma unroll
  for (int c = 0; c < C_CLS; ++c) {
    float e = __expf((s[c] - m) * invT);
    s[c] = e;
    sum += e;
  }
  float invsum = 1.0f / sum;
  float gP[C_CLS];
#pragma unroll
  for (int c = 0; c < C_CLS; ++c) gP[c] = gamma[c] * s[c] * invsum;

  const uint16_t* ob = (const uint16_t*)OUT + nl;
  float ss = 0.f;
  for (int i = i0; i < i0 + 64; ++i) {
    float term = 0.f;
#pragma unroll
    for (int c = 0; c < C_CLS; ++c)
      term += gP[c] * bf2f(ob[(size_t)((c << 10) + i) * ldo]);
    float g = bf2f(ob[(size_t)(10240 + i) * ldo]);
    float z = Zf[(size_t)i * N_DIM + n] * zs;
    float zn = z + eta * (g - term);
    Zf[(size_t)i * N_DIM + n] = zn;
    ss += zn * zn;
  }
  atomicAdd(&normsq_new[n], ss);
}

// ---------------- final column-normalize in place (Zf aliases d_out, fp32) ----------------
__global__ void normalize_z(float* __restrict__ Zf, const float* __restrict__ normsq) {
  int n = blockIdx.x * 256 + threadIdx.x;
  int i = blockIdx.y;
  float inv = rsqrtf(normsq[n]);
  Zf[(size_t)i * N_DIM + n] *= inv;
}

extern "C" void kernel_launch(void* const* d_in, const int* in_sizes, int n_in,
                              void* d_out, int out_size, void* d_ws, size_t ws_size,
                              hipStream_t stream) {
  (void)in_sizes; (void)n_in; (void)out_size;
  const float* Zin        = (const float*)d_in[0];
  const float* Elist      = (const float*)d_in[1];
  const float* Cslist     = (const float*)d_in[2];
  const float* gamma      = (const float*)d_in[3];
  const float* eta        = (const float*)d_in[4];
  const float* temperature= (const float*)d_in[5];

  float* Zf = (float*)d_out;  // evolving D x N fp32 features (unnormalized + normsq)

  auto align256 = [](size_t x) { return (x + 255) & ~(size_t)255; };
  size_t zbt_b = align256((size_t)N_DIM * D_DIM * 2);
  size_t wb_b  = align256((size_t)M_DIM * D_DIM * 2);
  size_t ns_b  = align256((size_t)N_DIM * 4);
  size_t fixed = zbt_b + wb_b + 2 * ns_b;

  int Nc = N_DIM;
  while (Nc > 256) {
    size_t need = fixed + align256((size_t)C_CLS * Nc * 4) + align256((size_t)M_DIM * Nc * 2);
    if (need <= ws_size) break;
    Nc >>= 1;
  }
  if (fixed + align256((size_t)C_CLS * Nc * 4) + align256((size_t)M_DIM * Nc * 2) > ws_size) {
    hipMemsetAsync(d_out, 0, (size_t)D_DIM * N_DIM * 4, stream);  // clean-fail signal
    return;
  }

  char* p = (char*)d_ws;
  bf16_t* ZbT  = (bf16_t*)p; p += zbt_b;
  bf16_t* Wb   = (bf16_t*)p; p += wb_b;
  float*  nsA  = (float*)p;  p += ns_b;
  float*  nsB  = (float*)p;  p += ns_b;
  float*  ssq  = (float*)p;  p += align256((size_t)C_CLS * Nc * 4);
  bf16_t* OUT  = (bf16_t*)p;

  float* ns_cur = nullptr;  // normsq of Zf's current (unnormalized) contents
  for (int l = 0; l < L_IT; ++l) {
    const float* Cs = Cslist + (size_t)l * C_CLS * D_DIM * D_DIM;
    const float* El = Elist  + (size_t)l * D_DIM * D_DIM;
    pack_bf16_k<<<2048, 256, 0, stream>>>((const float4*)Cs, (bf16x4*)Wb,
                                          C_CLS * D_DIM * D_DIM / 4);
    pack_bf16_k<<<1024, 256, 0, stream>>>((const float4*)El,
                                          (bf16x4*)(Wb + (size_t)C_CLS * D_DIM * D_DIM),
                                          D_DIM * D_DIM / 4);
    // ZbT = bf16(normalized Z_l); layer 0 also copies Zin into Zf
    transpose_zbt<<<dim3(N_DIM / 32, D_DIM / 32), 256, 0, stream>>>(
        l == 0 ? Zin : Zf, ZbT, l == 0 ? Zf : nullptr, ns_cur);

    float* ns_new = (ns_cur == nsA) ? nsB : nsA;
    hipMemsetAsync(ns_new, 0, (size_t)N_DIM * 4, stream);

    for (int n_off = 0; n_off < N_DIM; n_off += Nc) {
      hipMemsetAsync(ssq, 0, (size_t)C_CLS * Nc * 4, stream);
      gemm_wz8<<<dim3(NBM * (Nc / 256)), 512, 0, stream>>>(
          Wb, ZbT + (size_t)n_off * D_DIM, OUT, Nc, ssq);
      update_fused<<<dim3((Nc + 255) / 256, D_DIM / 64), 256, 0, stream>>>(
          OUT, Nc, Nc, ssq, gamma, eta, temperature, ns_cur, Zf, n_off, ns_new);
    }
    ns_cur = ns_new;
  }
  normalize_z<<<dim3(N_DIM / 256, D_DIM), 256, 0, stream>>>(Zf, ns_cur);
}

// Round 5
// 1277.850 us; speedup vs baseline: 1.5351x; 1.0284x over previous
//
#include <hip/hip_runtime.h>
#include <hip/hip_bf16.h>
#include <stdint.h>

#define D_DIM 1024
#define N_DIM 4096
#define C_CLS 10
#define L_IT 8
#define M_DIM 11264   // (C+1)*D
#define NBM 44        // M_DIM / 256

typedef __bf16 bf16_t;
typedef __bf16 bf16x8 __attribute__((ext_vector_type(8)));
typedef __bf16 bf16x4 __attribute__((ext_vector_type(4)));
typedef float  f32x4  __attribute__((ext_vector_type(4)));
typedef unsigned short u16x8 __attribute__((ext_vector_type(8)));

__device__ __forceinline__ float bf2f(uint16_t u) {
  union { uint32_t i; float f; } x; x.i = ((uint32_t)u) << 16; return x.f;
}

// ---------------- pack fp32 -> bf16 (x4 vectorized) ----------------
__global__ void pack_bf16_k(const float4* __restrict__ src, bf16x4* __restrict__ dst, int n4) {
  int stride = gridDim.x * blockDim.x;
  for (int i = blockIdx.x * blockDim.x + threadIdx.x; i < n4; i += stride) {
    float4 v = src[i];
    bf16x4 o;
    o[0] = (bf16_t)v.x; o[1] = (bf16_t)v.y; o[2] = (bf16_t)v.z; o[3] = (bf16_t)v.w;
    dst[i] = o;
  }
}

// ---------------- layer-0 init: Zin (D-major fp32) -> ZfT (N-major fp32) + ZbT (N-major bf16) ----------------
__global__ __launch_bounds__(256) void init_zt(const float* __restrict__ Zin,
                                               float* __restrict__ ZfT,
                                               bf16_t* __restrict__ ZbT) {
  __shared__ float tile[32][33];
  int tx = threadIdx.x & 31, ty = threadIdx.x >> 5;   // 32 x 8
  int nb = blockIdx.x, db = blockIdx.y;
  int n = nb * 32 + tx;
#pragma unroll
  for (int j = 0; j < 32; j += 8) {
    int d = db * 32 + ty + j;
    tile[ty + j][tx] = Zin[(size_t)d * N_DIM + n];   // tile[d_local][n_local]
  }
  __syncthreads();
  int d2 = db * 32 + tx;
#pragma unroll
  for (int j = 0; j < 32; j += 8) {
    int n2 = nb * 32 + ty + j;
    float v = tile[tx][ty + j];
    ZfT[(size_t)n2 * D_DIM + d2] = v;
    ZbT[(size_t)n2 * D_DIM + d2] = (bf16_t)v;
  }
}

// ---------------- final: ZfT (N-major fp32, normalized) -> d_out (D-major fp32) ----------------
__global__ __launch_bounds__(256) void final_out(const float* __restrict__ ZfT,
                                                 float* __restrict__ outp) {
  __shared__ float tile[32][33];
  int tx = threadIdx.x & 31, ty = threadIdx.x >> 5;
  int nb = blockIdx.x, db = blockIdx.y;
#pragma unroll
  for (int j = 0; j < 32; j += 8) {
    int n = nb * 32 + ty + j;
    int d = db * 32 + tx;
    tile[ty + j][tx] = ZfT[(size_t)n * D_DIM + d];   // tile[n_local][d_local]
  }
  __syncthreads();
#pragma unroll
  for (int j = 0; j < 32; j += 8) {
    int d2 = db * 32 + ty + j;
    int n2 = nb * 32 + tx;
    outp[(size_t)d2 * N_DIM + n2] = tile[tx][ty + j];
  }
}

// ================= 256x256 8-phase GEMM (T1+T2+T3/T4+T5), OUT transposed + fused class-ssq =================
// OUT_T[col][row] (bf16, [Nc][M_DIM]) = (Wb[M x 1024] * ZbT^T)^T ; ZbT is N-major [N x 1024].
// 512 threads = 8 waves (2M x 4N), per-wave 128x64 output, BK=64, K=1024 (16 tiles).
// LDS 128 KiB: A bufs at 0 / 16384, B bufs at 32768 / 49152 (elements).
// Swizzle (T2): 16B slot s -> s ^ (row&7), on pre-swizzled global src + ds_read.

#define STAGE_A(buf, h, t) do {                                                         \
    _Pragma("unroll") for (int e_ = 0; e_ < 2; ++e_) {                                  \
      const bf16_t* s_ = Wb + aoff0[e_] + (size_t)(h) * 65536 + (size_t)(t) * 64;       \
      __builtin_amdgcn_global_load_lds(                                                 \
        (const __attribute__((address_space(1))) void*)s_,                              \
        (__attribute__((address_space(3))) void*)(lds + (buf)*16384 + (h)*8192 + dstslot[e_]), \
        16, 0, 0);                                                                      \
    } } while (0)

#define STAGE_B(buf, h, t) do {                                                         \
    _Pragma("unroll") for (int e_ = 0; e_ < 2; ++e_) {                                  \
      const bf16_t* s_ = ZbT + boff0[e_] + (size_t)(h) * 32768 + (size_t)(t) * 64;      \
      __builtin_amdgcn_global_load_lds(                                                 \
        (const __attribute__((address_space(1))) void*)s_,                              \
        (__attribute__((address_space(3))) void*)(lds + 32768 + (buf)*16384 + (h)*8192 + dstslot[e_]), \
        16, 0, 0);                                                                      \
    } } while (0)

#define LOAD_A(buf, qm) do {                                                            \
    _Pragma("unroll") for (int f_ = 0; f_ < 4; ++f_)                                    \
      _Pragma("unroll") for (int kk_ = 0; kk_ < 2; ++kk_)                               \
        a[f_][kk_] = *(const bf16x8*)(lds + (buf)*16384 + (qm)*8192 + aRowBase + f_*1024 + sidx[kk_]); \
  } while (0)

#define LOAD_B(buf, qn) do {                                                            \
    _Pragma("unroll") for (int f_ = 0; f_ < 2; ++f_)                                    \
      _Pragma("unroll") for (int kk_ = 0; kk_ < 2; ++kk_)                               \
        b[f_][kk_] = *(const bf16x8*)(lds + 32768 + (buf)*16384 + (qn)*8192 + bRowBase + f_*1024 + sidx[kk_]); \
  } while (0)

#define MFMA_Q(qm, qn) do {                                                             \
    _Pragma("unroll") for (int mm_ = 0; mm_ < 4; ++mm_)                                 \
      _Pragma("unroll") for (int nn_ = 0; nn_ < 2; ++nn_)                               \
        _Pragma("unroll") for (int kk_ = 0; kk_ < 2; ++kk_)                             \
          acc[(qm)*4+mm_][(qn)*2+nn_] = __builtin_amdgcn_mfma_f32_16x16x32_bf16(        \
            a[mm_][kk_], b[nn_][kk_], acc[(qm)*4+mm_][(qn)*2+nn_], 0, 0, 0);            \
  } while (0)

#define PHASE(buf, qm, qn, DO_LOADA, STAGE_STMT, WAIT_STMT) do {                        \
    if (DO_LOADA) LOAD_A(buf, qm);                                                      \
    LOAD_B(buf, qn);                                                                    \
    STAGE_STMT;                                                                         \
    __builtin_amdgcn_s_barrier();                                                       \
    asm volatile("s_waitcnt lgkmcnt(0)" ::: "memory");                                  \
    __builtin_amdgcn_sched_barrier(0);                                                  \
    __builtin_amdgcn_s_setprio(1);                                                      \
    MFMA_Q(qm, qn);                                                                     \
    __builtin_amdgcn_s_setprio(0);                                                      \
    WAIT_STMT;                                                                          \
    __builtin_amdgcn_s_barrier();                                                       \
  } while (0)

__global__ __launch_bounds__(512, 2) void gemm_wz8(const bf16_t* __restrict__ Wb,
                                                   const bf16_t* __restrict__ ZbT,
                                                   bf16_t* __restrict__ OUT_T, int ldn,
                                                   float* __restrict__ ssq) {
  __shared__ __align__(16) bf16_t lds[65536];  // 128 KiB

  // T1: bijective XCD swizzle (m204)
  int nwg = gridDim.x;
  int bid = blockIdx.x;
  int q = nwg >> 3, r = nwg & 7;
  int xcd = bid & 7, idx = bid >> 3;
  int swz = (xcd < r ? xcd * (q + 1) : r * (q + 1) + (xcd - r) * q) + idx;
  int bm = swz % NBM, bn = swz / NBM;
  int m0 = bm * 256, n0 = bn * 256;

  int tid = threadIdx.x;
  int wave = tid >> 6, lane = tid & 63;
  int wrow = wave >> 2, wcol = wave & 3;
  int lm = lane & 15, lks = lane >> 4;   // 0..3
  int sw = lm & 7;

  // staging precompute
  size_t aoff0[2], boff0[2];
  int dstslot[2];
#pragma unroll
  for (int e = 0; e < 2; ++e) {
    int j = e * 512 + tid;
    int rih = j >> 3, sl = j & 7;
    int sg = sl ^ (rih & 7);                       // pre-swizzled global 16B slot
    int arow = (rih & 63) + ((rih >> 6) << 7);     // A: h adds +64 rows
    int brow = (rih & 31) + ((rih >> 5) << 6);     // B: h adds +32 rows
    aoff0[e] = (size_t)(m0 + arow) * 1024 + sg * 8;
    boff0[e] = (size_t)(n0 + brow) * 1024 + sg * 8;
    dstslot[e] = e * 4096 + wave * 512;            // element offset (wave-uniform)
  }

  // ds-read precompute
  int aRowBase = (wrow * 64 + lm) * 64;
  int bRowBase = (wcol * 32 + lm) * 64;
  int sidx[2] = { ((0 + lks) ^ sw) * 8, ((4 + lks) ^ sw) * 8 };

  f32x4 acc[8][4] = {};
  bf16x8 a[4][2], b[2][2];

  // prologue: T0 complete + T1.{A0,B0}; leave {T1.A0,T1.B0} outstanding
  STAGE_A(0, 0, 0); STAGE_A(0, 1, 0); STAGE_B(0, 0, 0); STAGE_B(0, 1, 0);
  STAGE_A(1, 0, 1); STAGE_B(1, 0, 1);
  asm volatile("s_waitcnt vmcnt(4)" ::: "memory");
  __builtin_amdgcn_s_barrier();

  for (int it = 0; it < 7; ++it) {
    int tO = 2 * it + 1, tN = 2 * it + 2, tM = 2 * it + 3;
    PHASE(0, 0, 0, 1, STAGE_A(1, 1, tO), );
    PHASE(0, 0, 1, 0, STAGE_B(1, 1, tO), );
    PHASE(0, 1, 0, 1, STAGE_A(0, 0, tN), );
    PHASE(0, 1, 1, 0, STAGE_A(0, 1, tN), asm volatile("s_waitcnt vmcnt(4)" ::: "memory"));
    PHASE(1, 0, 0, 1, STAGE_B(0, 0, tN), );
    PHASE(1, 0, 1, 0, STAGE_B(0, 1, tN), );
    PHASE(1, 1, 0, 1, STAGE_A(1, 0, tM), );
    PHASE(1, 1, 1, 0, STAGE_B(1, 0, tM), asm volatile("s_waitcnt vmcnt(4)" ::: "memory"));
  }
  PHASE(0, 0, 0, 1, STAGE_A(1, 1, 15), );
  PHASE(0, 0, 1, 0, STAGE_B(1, 1, 15), );
  PHASE(0, 1, 0, 1, , );
  PHASE(0, 1, 1, 0, , asm volatile("s_waitcnt vmcnt(0)" ::: "memory"));
  PHASE(1, 0, 0, 1, , );
  PHASE(1, 0, 1, 0, , );
  PHASE(1, 1, 0, 1, , );
  PHASE(1, 1, 1, 0, , );

  // C-write (transposed): OUT_T[col][row]; 4 acc rows are contiguous -> bf16x4 store
#pragma unroll
  for (int mf = 0; mf < 8; ++mf)
#pragma unroll
    for (int nf = 0; nf < 4; ++nf) {
      int col = n0 + wcol * 64 + nf * 16 + lm;
      int row = m0 + wrow * 128 + mf * 16 + lks * 4;
      bf16x4 v;
#pragma unroll
      for (int rr = 0; rr < 4; ++rr) v[rr] = (bf16_t)acc[mf][nf][rr];
      *(bf16x4*)(OUT_T + (size_t)col * M_DIM + row) = v;
    }

  // fused per-class column sum-of-squares (class blocks only; E rows skip)
  if (m0 < C_CLS * 1024) {
    int c = m0 >> 10;   // 256-row block lies entirely within one 1024-row class
#pragma unroll
    for (int nf = 0; nf < 4; ++nf) {
      float v = 0.f;
#pragma unroll
      for (int mf = 0; mf < 8; ++mf)
#pragma unroll
        for (int rr = 0; rr < 4; ++rr)
          v += acc[mf][nf][rr] * acc[mf][nf][rr];
      v += __shfl_xor(v, 16);
      v += __shfl_xor(v, 32);
      if (lks == 0)
        atomicAdd(&ssq[(size_t)c * ldn + n0 + wcol * 64 + nf * 16 + lm], v);
    }
  }
}

// ---------------- fused softmax + update + normalize + ZbT emit ----------------
// One wave per column. All accesses contiguous along i (N-major layouts).
__global__ __launch_bounds__(256) void update2(const bf16_t* __restrict__ OUT_T, int Nc,
                                               const float* __restrict__ ssq,
                                               const float* __restrict__ gamma,
                                               const float* __restrict__ etap,
                                               const float* __restrict__ tempr,
                                               float* __restrict__ ZfT,
                                               bf16_t* __restrict__ ZbT,
                                               int n_off) {
  int wv = threadIdx.x >> 6, lane = threadIdx.x & 63;
  int nl = blockIdx.x * 4 + wv;
  if (nl >= Nc) return;
  int n = n_off + nl;
  float eta = etap[0], invT = 1.0f / tempr[0];

  // softmax over classes (redundant per lane; broadcast loads)
  float s[C_CLS], m = -1e30f;
#pragma unroll
  for (int c = 0; c < C_CLS; ++c) {
    float sim = -sqrtf(ssq[(size_t)c * Nc + nl]);
    s[c] = sim;
    m = fmaxf(m, sim);
  }
  float sum = 0.f;
#pragma unroll
  for (int c = 0; c < C_CLS; ++c) {
    float e = __expf((s[c] - m) * invT);
    s[c] = e;
    sum += e;
  }
  float invsum = 1.0f / sum;
  float gP[C_CLS];
#pragma unroll
  for (int c = 0; c < C_CLS; ++c) gP[c] = gamma[c] * s[c] * invsum;

  // lane owns i in [lane*16, lane*16+16)
  const u16x8* ob = (const u16x8*)(OUT_T + (size_t)nl * M_DIM) + lane * 2;
  float term[16] = {};
#pragma unroll
  for (int c = 0; c < C_CLS; ++c) {
    u16x8 v0 = ob[c * 128], v1 = ob[c * 128 + 1];
#pragma unroll
    for (int j = 0; j < 8; ++j) {
      term[j]     += gP[c] * bf2f(v0[j]);
      term[8 + j] += gP[c] * bf2f(v1[j]);
    }
  }
  u16x8 g0 = ob[C_CLS * 128], g1 = ob[C_CLS * 128 + 1];

  const f32x4* zp = (const f32x4*)(ZfT + (size_t)n * D_DIM) + lane * 4;
  f32x4 z[4] = { zp[0], zp[1], zp[2], zp[3] };

  float zn[16];
  float ss = 0.f;
#pragma unroll
  for (int j = 0; j < 16; ++j) {
    float g = bf2f(j < 8 ? g0[j & 7] : g1[j & 7]);
    float v = z[j >> 2][j & 3] + eta * (g - term[j]);
    zn[j] = v;
    ss += v * v;
  }
  // wave-wide reduce (64 lanes)
#pragma unroll
  for (int k = 1; k < 64; k <<= 1) ss += __shfl_xor(ss, k);
  float inv = rsqrtf(ss);

  f32x4* zo = (f32x4*)(ZfT + (size_t)n * D_DIM) + lane * 4;
  bf16x8* bo = (bf16x8*)(ZbT + (size_t)n * D_DIM) + lane * 2;
#pragma unroll
  for (int q4 = 0; q4 < 4; ++q4) {
    f32x4 o;
#pragma unroll
    for (int j = 0; j < 4; ++j) o[j] = zn[q4 * 4 + j] * inv;
    zo[q4] = o;
  }
#pragma unroll
  for (int h = 0; h < 2; ++h) {
    bf16x8 o;
#pragma unroll
    for (int j = 0; j < 8; ++j) o[j] = (bf16_t)(zn[h * 8 + j] * inv);
    bo[h] = o;
  }
}

extern "C" void kernel_launch(void* const* d_in, const int* in_sizes, int n_in,
                              void* d_out, int out_size, void* d_ws, size_t ws_size,
                              hipStream_t stream) {
  (void)in_sizes; (void)n_in; (void)out_size;
  const float* Zin        = (const float*)d_in[0];
  const float* Elist      = (const float*)d_in[1];
  const float* Cslist     = (const float*)d_in[2];
  const float* gamma      = (const float*)d_in[3];
  const float* eta        = (const float*)d_in[4];
  const float* temperature= (const float*)d_in[5];

  auto align256 = [](size_t x) { return (x + 255) & ~(size_t)255; };
  size_t zbt_b = align256((size_t)N_DIM * D_DIM * 2);
  size_t zft_b = align256((size_t)N_DIM * D_DIM * 4);
  size_t wb_b  = align256((size_t)M_DIM * D_DIM * 2);
  size_t fixed = zbt_b + zft_b + wb_b;

  int Nc = N_DIM;
  while (Nc > 256) {
    size_t need = fixed + align256((size_t)C_CLS * Nc * 4) + align256((size_t)M_DIM * Nc * 2);
    if (need <= ws_size) break;
    Nc >>= 1;
  }
  if (fixed + align256((size_t)C_CLS * Nc * 4) + align256((size_t)M_DIM * Nc * 2) > ws_size) {
    hipMemsetAsync(d_out, 0, (size_t)D_DIM * N_DIM * 4, stream);  // clean-fail signal
    return;
  }

  char* p = (char*)d_ws;
  bf16_t* ZbT  = (bf16_t*)p; p += zbt_b;
  float*  ZfT  = (float*)p;  p += zft_b;
  bf16_t* Wb   = (bf16_t*)p; p += wb_b;
  float*  ssq  = (float*)p;  p += align256((size_t)C_CLS * Nc * 4);
  bf16_t* OUT_T= (bf16_t*)p;

  init_zt<<<dim3(N_DIM / 32, D_DIM / 32), 256, 0, stream>>>(Zin, ZfT, ZbT);

  for (int l = 0; l < L_IT; ++l) {
    const float* Cs = Cslist + (size_t)l * C_CLS * D_DIM * D_DIM;
    const float* El = Elist  + (size_t)l * D_DIM * D_DIM;
    pack_bf16_k<<<2048, 256, 0, stream>>>((const float4*)Cs, (bf16x4*)Wb,
                                          C_CLS * D_DIM * D_DIM / 4);
    pack_bf16_k<<<1024, 256, 0, stream>>>((const float4*)El,
                                          (bf16x4*)(Wb + (size_t)C_CLS * D_DIM * D_DIM),
                                          D_DIM * D_DIM / 4);

    for (int n_off = 0; n_off < N_DIM; n_off += Nc) {
      hipMemsetAsync(ssq, 0, (size_t)C_CLS * Nc * 4, stream);
      gemm_wz8<<<dim3(NBM * (Nc / 256)), 512, 0, stream>>>(
          Wb, ZbT + (size_t)n_off * D_DIM, OUT_T, Nc, ssq);
      update2<<<dim3(Nc / 4), 256, 0, stream>>>(
          OUT_T, Nc, ssq, gamma, eta, temperature, ZfT, ZbT, n_off);
    }
  }
  final_out<<<dim3(N_DIM / 32, D_DIM / 32), 256, 0, stream>>>(ZfT, (float*)d_out);
}

// Round 6
// 1244.117 us; speedup vs baseline: 1.5767x; 1.0271x over previous
//
#include <hip/hip_runtime.h>
#include <hip/hip_bf16.h>
#include <stdint.h>

#define D_DIM 1024
#define N_DIM 4096
#define C_CLS 10
#define L_IT 8
#define M_DIM 11264   // (C+1)*D
#define NBM 44        // M_DIM / 256

typedef __bf16 bf16_t;
typedef __bf16 bf16x8 __attribute__((ext_vector_type(8)));
typedef __bf16 bf16x4 __attribute__((ext_vector_type(4)));
typedef float  f32x4  __attribute__((ext_vector_type(4)));
typedef unsigned short u16x8 __attribute__((ext_vector_type(8)));

__device__ __forceinline__ float bf2f(uint16_t u) {
  union { uint32_t i; float f; } x; x.i = ((uint32_t)u) << 16; return x.f;
}

// ---------------- pack W = [Cs ; E] fp32 -> bf16 (one kernel) ----------------
__global__ __launch_bounds__(256) void pack_w(const float4* __restrict__ Cs,
                                              const float4* __restrict__ El,
                                              bf16x4* __restrict__ dst) {
  const int CS4 = C_CLS * D_DIM * D_DIM / 4;          // 2621440
  int i = blockIdx.x * 256 + threadIdx.x;             // < 2883584
  float4 v = (i < CS4) ? Cs[i] : El[i - CS4];
  bf16x4 o;
  o[0] = (bf16_t)v.x; o[1] = (bf16_t)v.y; o[2] = (bf16_t)v.z; o[3] = (bf16_t)v.w;
  dst[i] = o;
}

// ---------------- layer-0 init: Zin (D-major fp32) -> ZfT (N-major fp32) + ZbT (N-major bf16) ----------------
__global__ __launch_bounds__(256) void init_zt(const float* __restrict__ Zin,
                                               float* __restrict__ ZfT,
                                               bf16_t* __restrict__ ZbT) {
  __shared__ float tile[32][33];
  int tx = threadIdx.x & 31, ty = threadIdx.x >> 5;   // 32 x 8
  int nb = blockIdx.x, db = blockIdx.y;
  int n = nb * 32 + tx;
#pragma unroll
  for (int j = 0; j < 32; j += 8) {
    int d = db * 32 + ty + j;
    tile[ty + j][tx] = Zin[(size_t)d * N_DIM + n];
  }
  __syncthreads();
  int d2 = db * 32 + tx;
#pragma unroll
  for (int j = 0; j < 32; j += 8) {
    int n2 = nb * 32 + ty + j;
    float v = tile[tx][ty + j];
    ZfT[(size_t)n2 * D_DIM + d2] = v;
    ZbT[(size_t)n2 * D_DIM + d2] = (bf16_t)v;
  }
}

// ---------------- final: ZfT (N-major fp32, normalized) -> d_out (D-major fp32) ----------------
__global__ __launch_bounds__(256) void final_out(const float* __restrict__ ZfT,
                                                 float* __restrict__ outp) {
  __shared__ float tile[32][33];
  int tx = threadIdx.x & 31, ty = threadIdx.x >> 5;
  int nb = blockIdx.x, db = blockIdx.y;
#pragma unroll
  for (int j = 0; j < 32; j += 8) {
    int n = nb * 32 + ty + j;
    int d = db * 32 + tx;
    tile[ty + j][tx] = ZfT[(size_t)n * D_DIM + d];
  }
  __syncthreads();
#pragma unroll
  for (int j = 0; j < 32; j += 8) {
    int d2 = db * 32 + ty + j;
    int n2 = nb * 32 + tx;
    outp[(size_t)d2 * N_DIM + n2] = tile[tx][ty + j];
  }
}

// ================= 256x256 8-phase GEMM (T1+T2+T3/T4+T5), OUT transposed + fused class-ssq =================
// OUT_T[col][row] (bf16, [Nc][M_DIM]) = (Wb[M x 1024] * ZbT^T)^T ; ZbT is N-major [N x 1024].
// 512 threads = 8 waves (2M x 4N), per-wave 128x64 output, BK=64, K=1024 (16 tiles).
// B-fragments held across qm in two register sets (b0 for qn=0, b1 for qn=1):
// 48 ds_read_b128/wave/iter instead of 64 (LDS-read-bound regime).

#define STAGE_A(buf, h, t) do {                                                         \
    _Pragma("unroll") for (int e_ = 0; e_ < 2; ++e_) {                                  \
      const bf16_t* s_ = Wb + aoff0[e_] + (size_t)(h) * 65536 + (size_t)(t) * 64;       \
      __builtin_amdgcn_global_load_lds(                                                 \
        (const __attribute__((address_space(1))) void*)s_,                              \
        (__attribute__((address_space(3))) void*)(lds + (buf)*16384 + (h)*8192 + dstslot[e_]), \
        16, 0, 0);                                                                      \
    } } while (0)

#define STAGE_B(buf, h, t) do {                                                         \
    _Pragma("unroll") for (int e_ = 0; e_ < 2; ++e_) {                                  \
      const bf16_t* s_ = ZbT + boff0[e_] + (size_t)(h) * 32768 + (size_t)(t) * 64;      \
      __builtin_amdgcn_global_load_lds(                                                 \
        (const __attribute__((address_space(1))) void*)s_,                              \
        (__attribute__((address_space(3))) void*)(lds + 32768 + (buf)*16384 + (h)*8192 + dstslot[e_]), \
        16, 0, 0);                                                                      \
    } } while (0)

#define LOAD_A(buf, qm) do {                                                            \
    _Pragma("unroll") for (int f_ = 0; f_ < 4; ++f_)                                    \
      _Pragma("unroll") for (int kk_ = 0; kk_ < 2; ++kk_)                               \
        a[f_][kk_] = *(const bf16x8*)(lds + (buf)*16384 + (qm)*8192 + aRowBase + f_*1024 + sidx[kk_]); \
  } while (0)

#define LOAD_Bq(buf, qn, arr) do {                                                      \
    _Pragma("unroll") for (int f_ = 0; f_ < 2; ++f_)                                    \
      _Pragma("unroll") for (int kk_ = 0; kk_ < 2; ++kk_)                               \
        arr[f_][kk_] = *(const bf16x8*)(lds + 32768 + (buf)*16384 + (qn)*8192 + bRowBase + f_*1024 + sidx[kk_]); \
  } while (0)

#define MFMA_Q(qm, qn, arr) do {                                                        \
    _Pragma("unroll") for (int mm_ = 0; mm_ < 4; ++mm_)                                 \
      _Pragma("unroll") for (int nn_ = 0; nn_ < 2; ++nn_)                               \
        _Pragma("unroll") for (int kk_ = 0; kk_ < 2; ++kk_)                             \
          acc[(qm)*4+mm_][(qn)*2+nn_] = __builtin_amdgcn_mfma_f32_16x16x32_bf16(        \
            a[mm_][kk_], arr[nn_][kk_], acc[(qm)*4+mm_][(qn)*2+nn_], 0, 0, 0);          \
  } while (0)

#define PHASE(qm, qn, arr, LOAD_STMT, STAGE_STMT, WAIT_STMT) do {                       \
    LOAD_STMT;                                                                          \
    STAGE_STMT;                                                                         \
    __builtin_amdgcn_s_barrier();                                                       \
    asm volatile("s_waitcnt lgkmcnt(0)" ::: "memory");                                  \
    __builtin_amdgcn_sched_barrier(0);                                                  \
    __builtin_amdgcn_s_setprio(1);                                                      \
    MFMA_Q(qm, qn, arr);                                                                \
    __builtin_amdgcn_s_setprio(0);                                                      \
    WAIT_STMT;                                                                          \
    __builtin_amdgcn_s_barrier();                                                       \
  } while (0)

__global__ __launch_bounds__(512, 2) void gemm_wz8(const bf16_t* __restrict__ Wb,
                                                   const bf16_t* __restrict__ ZbT,
                                                   bf16_t* __restrict__ OUT_T, int ldn,
                                                   float* __restrict__ ssq) {
  __shared__ __align__(16) bf16_t lds[65536];  // 128 KiB

  // T1: bijective XCD swizzle (m204)
  int nwg = gridDim.x;
  int bid = blockIdx.x;
  int q = nwg >> 3, r = nwg & 7;
  int xcd = bid & 7, idx = bid >> 3;
  int swz = (xcd < r ? xcd * (q + 1) : r * (q + 1) + (xcd - r) * q) + idx;
  int bm = swz % NBM, bn = swz / NBM;
  int m0 = bm * 256, n0 = bn * 256;

  int tid = threadIdx.x;
  int wave = tid >> 6, lane = tid & 63;
  int wrow = wave >> 2, wcol = wave & 3;
  int lm = lane & 15, lks = lane >> 4;   // 0..3
  int sw = lm & 7;

  // staging precompute
  size_t aoff0[2], boff0[2];
  int dstslot[2];
#pragma unroll
  for (int e = 0; e < 2; ++e) {
    int j = e * 512 + tid;
    int rih = j >> 3, sl = j & 7;
    int sg = sl ^ (rih & 7);                       // pre-swizzled global 16B slot
    int arow = (rih & 63) + ((rih >> 6) << 7);     // A halves: {0-63,128-191} / +64
    int brow = (rih & 31) + ((rih >> 5) << 6);     // B halves: {0-31,64-95,...} / +32
    aoff0[e] = (size_t)(m0 + arow) * 1024 + sg * 8;
    boff0[e] = (size_t)(n0 + brow) * 1024 + sg * 8;
    dstslot[e] = e * 4096 + wave * 512;            // element offset (wave-uniform)
  }

  // ds-read precompute
  int aRowBase = (wrow * 64 + lm) * 64;
  int bRowBase = (wcol * 32 + lm) * 64;
  int sidx[2] = { ((0 + lks) ^ sw) * 8, ((4 + lks) ^ sw) * 8 };

  f32x4 acc[8][4] = {};
  bf16x8 a[4][2], b0[2][2], b1[2][2];

  // prologue: T0 complete + T1.{A0,B0}; leave {T1.A0,T1.B0} outstanding
  STAGE_A(0, 0, 0); STAGE_A(0, 1, 0); STAGE_B(0, 0, 0); STAGE_B(0, 1, 0);
  STAGE_A(1, 0, 1); STAGE_B(1, 0, 1);
  asm volatile("s_waitcnt vmcnt(4)" ::: "memory");
  __builtin_amdgcn_s_barrier();

  for (int it = 0; it < 7; ++it) {
    int tO = 2 * it + 1, tN = 2 * it + 2, tM = 2 * it + 3;
    PHASE(0, 0, b0, LOAD_A(0,0); LOAD_Bq(0,0,b0), STAGE_A(1, 1, tO), );
    PHASE(0, 1, b1, LOAD_Bq(0,1,b1),              STAGE_B(1, 1, tO), );
    PHASE(1, 0, b0, LOAD_A(0,1),                  STAGE_A(0, 0, tN), );
    PHASE(1, 1, b1, ,                             STAGE_A(0, 1, tN), asm volatile("s_waitcnt vmcnt(4)" ::: "memory"));
    PHASE(0, 0, b0, LOAD_A(1,0); LOAD_Bq(1,0,b0), STAGE_B(0, 0, tN), );
    PHASE(0, 1, b1, LOAD_Bq(1,1,b1),              STAGE_B(0, 1, tN), );
    PHASE(1, 0, b0, LOAD_A(1,1),                  STAGE_A(1, 0, tM), );
    PHASE(1, 1, b1, ,                             STAGE_B(1, 0, tM), asm volatile("s_waitcnt vmcnt(4)" ::: "memory"));
  }
  // epilogue: tiles 14 (buf0), 15 (buf1)
  PHASE(0, 0, b0, LOAD_A(0,0); LOAD_Bq(0,0,b0), STAGE_A(1, 1, 15), );
  PHASE(0, 1, b1, LOAD_Bq(0,1,b1),              STAGE_B(1, 1, 15), );
  PHASE(1, 0, b0, LOAD_A(0,1),                  , );
  PHASE(1, 1, b1, ,                             , asm volatile("s_waitcnt vmcnt(0)" ::: "memory"));
  PHASE(0, 0, b0, LOAD_A(1,0); LOAD_Bq(1,0,b0), , );
  PHASE(0, 1, b1, LOAD_Bq(1,1,b1),              , );
  PHASE(1, 0, b0, LOAD_A(1,1),                  , );
  PHASE(1, 1, b1, ,                             , );

  // C-write (transposed): OUT_T[col][row]; 4 acc rows contiguous -> 8B store
#pragma unroll
  for (int mf = 0; mf < 8; ++mf)
#pragma unroll
    for (int nf = 0; nf < 4; ++nf) {
      int col = n0 + wcol * 64 + nf * 16 + lm;
      int row = m0 + wrow * 128 + mf * 16 + lks * 4;
      bf16x4 v;
#pragma unroll
      for (int rr = 0; rr < 4; ++rr) v[rr] = (bf16_t)acc[mf][nf][rr];
      *(bf16x4*)(OUT_T + (size_t)col * M_DIM + row) = v;
    }

  // fused per-class column sum-of-squares (class blocks only; E rows skip)
  if (m0 < C_CLS * 1024) {
    int c = m0 >> 10;
#pragma unroll
    for (int nf = 0; nf < 4; ++nf) {
      float v = 0.f;
#pragma unroll
      for (int mf = 0; mf < 8; ++mf)
#pragma unroll
        for (int rr = 0; rr < 4; ++rr)
          v += acc[mf][nf][rr] * acc[mf][nf][rr];
      v += __shfl_xor(v, 16);
      v += __shfl_xor(v, 32);
      if (lks == 0)
        atomicAdd(&ssq[(size_t)c * ldn + n0 + wcol * 64 + nf * 16 + lm], v);
    }
  }
}

// ---------------- fused softmax + update + normalize + ZbT emit ----------------
__global__ __launch_bounds__(256) void update2(const bf16_t* __restrict__ OUT_T, int Nc,
                                               const float* __restrict__ ssq,
                                               const float* __restrict__ gamma,
                                               const float* __restrict__ etap,
                                               const float* __restrict__ tempr,
                                               float* __restrict__ ZfT,
                                               bf16_t* __restrict__ ZbT,
                                               int n_off) {
  int wv = threadIdx.x >> 6, lane = threadIdx.x & 63;
  int nl = blockIdx.x * 4 + wv;
  if (nl >= Nc) return;
  int n = n_off + nl;
  float eta = etap[0], invT = 1.0f / tempr[0];

  float s[C_CLS], m = -1e30f;
#pragma unroll
  for (int c = 0; c < C_CLS; ++c) {
    float sim = -sqrtf(ssq[(size_t)c * Nc + nl]);
    s[c] = sim;
    m = fmaxf(m, sim);
  }
  float sum = 0.f;
#pragma unroll
  for (int c = 0; c < C_CLS; ++c) {
    float e = __expf((s[c] - m) * invT);
    s[c] = e;
    sum += e;
  }
  float invsum = 1.0f / sum;
  float gP[C_CLS];
#pragma unroll
  for (int c = 0; c < C_CLS; ++c) gP[c] = gamma[c] * s[c] * invsum;

  const u16x8* ob = (const u16x8*)(OUT_T + (size_t)nl * M_DIM) + lane * 2;
  float term[16] = {};
#pragma unroll
  for (int c = 0; c < C_CLS; ++c) {
    u16x8 v0 = ob[c * 128], v1 = ob[c * 128 + 1];
#pragma unroll
    for (int j = 0; j < 8; ++j) {
      term[j]     += gP[c] * bf2f(v0[j]);
      term[8 + j] += gP[c] * bf2f(v1[j]);
    }
  }
  u16x8 g0 = ob[C_CLS * 128], g1 = ob[C_CLS * 128 + 1];

  const f32x4* zp = (const f32x4*)(ZfT + (size_t)n * D_DIM) + lane * 4;
  f32x4 z[4] = { zp[0], zp[1], zp[2], zp[3] };

  float zn[16];
  float ss = 0.f;
#pragma unroll
  for (int j = 0; j < 16; ++j) {
    float g = bf2f(j < 8 ? g0[j & 7] : g1[j & 7]);
    float v = z[j >> 2][j & 3] + eta * (g - term[j]);
    zn[j] = v;
    ss += v * v;
  }
#pragma unroll
  for (int k = 1; k < 64; k <<= 1) ss += __shfl_xor(ss, k);
  float inv = rsqrtf(ss);

  f32x4* zo = (f32x4*)(ZfT + (size_t)n * D_DIM) + lane * 4;
  bf16x8* bo = (bf16x8*)(ZbT + (size_t)n * D_DIM) + lane * 2;
#pragma unroll
  for (int q4 = 0; q4 < 4; ++q4) {
    f32x4 o;
#pragma unroll
    for (int j = 0; j < 4; ++j) o[j] = zn[q4 * 4 + j] * inv;
    zo[q4] = o;
  }
#pragma unroll
  for (int h = 0; h < 2; ++h) {
    bf16x8 o;
#pragma unroll
    for (int j = 0; j < 8; ++j) o[j] = (bf16_t)(zn[h * 8 + j] * inv);
    bo[h] = o;
  }
}

extern "C" void kernel_launch(void* const* d_in, const int* in_sizes, int n_in,
                              void* d_out, int out_size, void* d_ws, size_t ws_size,
                              hipStream_t stream) {
  (void)in_sizes; (void)n_in; (void)out_size;
  const float* Zin        = (const float*)d_in[0];
  const float* Elist      = (const float*)d_in[1];
  const float* Cslist     = (const float*)d_in[2];
  const float* gamma      = (const float*)d_in[3];
  const float* eta        = (const float*)d_in[4];
  const float* temperature= (const float*)d_in[5];

  auto align256 = [](size_t x) { return (x + 255) & ~(size_t)255; };
  size_t zbt_b = align256((size_t)N_DIM * D_DIM * 2);
  size_t zft_b = align256((size_t)N_DIM * D_DIM * 4);
  size_t wb_b  = align256((size_t)M_DIM * D_DIM * 2);
  size_t ssq_b = align256((size_t)L_IT * C_CLS * N_DIM * 4);
  size_t out_b = align256((size_t)M_DIM * N_DIM * 2);

  if (zbt_b + zft_b + wb_b + ssq_b + out_b > ws_size) {
    hipMemsetAsync(d_out, 0, (size_t)D_DIM * N_DIM * 4, stream);  // clean-fail signal
    return;
  }

  char* p = (char*)d_ws;
  bf16_t* ZbT  = (bf16_t*)p; p += zbt_b;
  float*  ZfT  = (float*)p;  p += zft_b;
  bf16_t* Wb   = (bf16_t*)p; p += wb_b;
  float*  ssq  = (float*)p;  p += ssq_b;
  bf16_t* OUT_T= (bf16_t*)p;

  hipMemsetAsync(ssq, 0, (size_t)L_IT * C_CLS * N_DIM * 4, stream);
  init_zt<<<dim3(N_DIM / 32, D_DIM / 32), 256, 0, stream>>>(Zin, ZfT, ZbT);

  for (int l = 0; l < L_IT; ++l) {
    const float* Cs = Cslist + (size_t)l * C_CLS * D_DIM * D_DIM;
    const float* El = Elist  + (size_t)l * D_DIM * D_DIM;
    float* ssq_l = ssq + (size_t)l * C_CLS * N_DIM;

    pack_w<<<dim3(M_DIM * D_DIM / 4 / 256), 256, 0, stream>>>(
        (const float4*)Cs, (const float4*)El, (bf16x4*)Wb);

    gemm_wz8<<<dim3(NBM * (N_DIM / 256)), 512, 0, stream>>>(
        Wb, ZbT, OUT_T, N_DIM, ssq_l);
    update2<<<dim3(N_DIM / 4), 256, 0, stream>>>(
        OUT_T, N_DIM, ssq_l, gamma, eta, temperature, ZfT, ZbT, 0);
  }
  final_out<<<dim3(N_DIM / 32, D_DIM / 32), 256, 0, stream>>>(ZfT, (float*)d_out);
}